// Round 12
// baseline (422.122 us; speedup 1.0000x reference)
//
#include <hip/hip_runtime.h>

// MultiHeadAttention_137438953529 on gfx950.
// B=8, S=1024, E=1024, H=16, D=64.  The reference's reshapes are flat
// reinterpretations => attention mixes only groups of 8 consecutive rows of
// the (8192 x 1024) projected matrices, per 64-wide head slice.
//
// R12: LDS-bandwidth model (explains R1-R11's 14-18% cluster): every variant
// moved ~0.042-0.053 LDS-bytes/FLOP -> ~1100cy/iter at 128B/cy, MFMA only
// 234cy/SIMD -> 17%.  Cut 2x: A NEVER touches LDS.  A-fragments are lane-
// private -> loaded direct to registers with a 2-iteration ping-pong
// (R8's retry, fixed: R8 only had 1-iter slack).  Iter kt: consume A(kt)
// (issued 2 iters ago), stage B(kt+1) via glds, 16 MFMA, issue A(kt+2),
// fence vmcnt(8) (retires A(kt+1)+glds(kt+1), leaves A(kt+2) in flight).
// LDS = B only (2x8KB): 24KB/block-iter = 0.023 B/FLOP.  No ds_write, no
// lgkm wait.  cvt_pk per-m inside the MFMA loop (regs ~163 @ (256,3)).
// Kept verbatim: XCD-family decode, B source-XOR (0 conflicts), epilogue,
// cvt_w, attn.

typedef __attribute__((ext_vector_type(4))) float f32x4;
typedef __attribute__((ext_vector_type(8))) short bf16x8;   // MFMA A/B fragment
typedef __attribute__((ext_vector_type(8))) unsigned short u16x8;

#define WAIT_VM(n) asm volatile("s_waitcnt vmcnt(" #n ")" ::: "memory")
#define SCHED0 __builtin_amdgcn_sched_barrier(0)
#define BARRIER __builtin_amdgcn_s_barrier()

__device__ __forceinline__ unsigned short f2bf(float f) {
  unsigned int u = __builtin_bit_cast(unsigned int, f);
  u += 0x7fffu + ((u >> 16) & 1u);          // round-to-nearest-even
  return (unsigned short)(u >> 16);
}
__device__ __forceinline__ float bf2f(unsigned short b) {
  return __builtin_bit_cast(float, ((unsigned int)b) << 16);
}
__device__ __forceinline__ u16x8 pack8(f32x4 a, f32x4 b) {
  u16x8 o;
  o[0] = f2bf(a[0]); o[1] = f2bf(a[1]); o[2] = f2bf(a[2]); o[3] = f2bf(a[3]);
  o[4] = f2bf(b[0]); o[5] = f2bf(b[1]); o[6] = f2bf(b[2]); o[7] = f2bf(b[3]);
  return o;
}
// 8x f32 -> 8x bf16 via packed cvt (RNE), as MFMA fragment
__device__ __forceinline__ bf16x8 cvt8(f32x4 a, f32x4 b) {
  union { unsigned int u[4]; bf16x8 v; } r;
  asm("v_cvt_pk_bf16_f32 %0, %1, %2" : "=v"(r.u[0]) : "v"(a[0]), "v"(a[1]));
  asm("v_cvt_pk_bf16_f32 %0, %1, %2" : "=v"(r.u[1]) : "v"(a[2]), "v"(a[3]));
  asm("v_cvt_pk_bf16_f32 %0, %1, %2" : "=v"(r.u[2]) : "v"(b[0]), "v"(b[1]));
  asm("v_cvt_pk_bf16_f32 %0, %1, %2" : "=v"(r.u[3]) : "v"(b[2]), "v"(b[3]));
  return r.v;
}

__device__ __forceinline__ void gload_lds16(const void* g, void* l) {
  __builtin_amdgcn_global_load_lds(
      (const __attribute__((address_space(1))) unsigned int*)g,
      (__attribute__((address_space(3))) unsigned int*)l, 16, 0, 0);
}

// --------------------------------------------------- W -> bf16 (linear layout)
__global__ __launch_bounds__(256) void cvt_w(const float* __restrict__ Wq,
                                             const float* __restrict__ Wk,
                                             const float* __restrict__ Wv,
                                             unsigned short* __restrict__ Wb) {
  int i = blockIdx.x * 256 + threadIdx.x;     // 0 .. 393216 (3 * 131072 chunks of 8)
  int proj = i >> 17;
  int local = i & 131071;
  const float* src = (proj == 0 ? Wq : proj == 1 ? Wk : Wv) + (size_t)local * 8;
  f32x4 a = reinterpret_cast<const f32x4*>(src)[0];
  f32x4 b = reinterpret_cast<const f32x4*>(src)[1];
  *reinterpret_cast<u16x8*>(Wb + (size_t)proj * 1048576 + (size_t)local * 8) = pack8(a, b);
}

// ------------------------------------------------------------ QKV projection
// C[8192x1024] = X @ W^T + bias per proj.  BM=BN=128, BK=32, 256 threads,
// 4 waves (2x2), per-wave 64x64 (4x4 frags of 16x16x32 bf16 MFMA), 32 K-iters.
__global__ __launch_bounds__(256, 3) void gemm12(
    const float* __restrict__ Xq, const float* __restrict__ Xk, const float* __restrict__ Xv,
    const unsigned short* __restrict__ Wb,
    const float* __restrict__ bq, const float* __restrict__ bk, const float* __restrict__ bv,
    unsigned short* __restrict__ QKV) {
  // XCD-family decode: XCD c (dispatch round-robin d%8) owns x in [8c,8c+8);
  // consecutive-in-time blocks on one XCD share x (X panel L2-resident, read
  // ~once from HBM) and sweep y (W panels cycle; L2+L3 absorb).
  const int d = blockIdx.x;
  const int xcd = d & 7;
  const int k5 = d >> 3;
  const int y = k5 & 7;
  const int rest = k5 >> 3;       // 0..23
  const int proj = rest >> 3;     // 0..2
  const int xg = rest & 7;
  const int x = xcd * 8 + xg;     // 0..63

  const float* X = (proj == 0) ? Xq : (proj == 1) ? Xk : Xv;
  const float* bias = (proj == 0) ? bq : (proj == 1) ? bk : bv;
  const unsigned short* W = Wb + (size_t)proj * 1048576;
  unsigned short* O = QKV + (size_t)proj * 8388608;

  const int rowBase = x * 128;
  const int colBase = y * 128;

  __shared__ alignas(16) unsigned short Bs[2][4096];   // [128 rows][32 k] bf16, chunk-XOR'd

  const int t = threadIdx.x;
  const int l = t & 63;
  const int w = t >> 6;
  const int wr = w >> 1, wc = w & 1;
  const int fr = l & 15;          // fragment row within 16
  const int fg = l >> 4;          // fragment k-group (8-elem chunk)

  f32x4 acc[4][4];
#pragma unroll
  for (int m = 0; m < 4; ++m)
#pragma unroll
    for (int n = 0; n < 4; ++n) acc[m][n] = f32x4{0.f, 0.f, 0.f, 0.f};

  // B fragment read offsets (ushort units): logical chunk g of row r lives at
  // physical chunk g ^ ((r>>1)&3)   [R4-proven: 0 bank conflicts]
  int boff[4];
#pragma unroll
  for (int n = 0; n < 4; ++n) {
    const int row = wc * 64 + n * 16 + fr;
    boff[n] = row * 32 + ((fg ^ ((row >> 1) & 3)) * 8);
  }

  // A: per-lane direct-to-register fragment loads.  Lane (fr,fg) of frag m:
  // row rowBase + wr*64 + m*16 + fr, k = kt*32 + fg*8 .. +8 (two f32x4).
  const float* aBase = X + (size_t)(rowBase + wr * 64 + fr) * 1024 + fg * 8;
#define ISSUE_A(kt, R)                                                            \
  {                                                                               \
    const float* ap = aBase + (kt) * 32;                                          \
    _Pragma("unroll") for (int m = 0; m < 4; ++m) {                               \
      R[2 * m]     = *reinterpret_cast<const f32x4*>(ap + m * 16384);             \
      R[2 * m + 1] = *reinterpret_cast<const f32x4*>(ap + m * 16384 + 4);         \
    }                                                                             \
  }

  // B staging (R4-identical): thread t, call j: linear dest byte
  // o=(j*4+w)*1024+l*16; row=o>>6, phys chunk=l&3; src chunk=(l&3)^((row>>1)&3)
  const int srow0 = w * 16 + (l >> 2);
  const int sc = l & 3;
#define STAGE_B(dst, kt)                                                          \
  {                                                                               \
    _Pragma("unroll") for (int j = 0; j < 2; ++j) {                               \
      const int row = j * 64 + srow0;                                             \
      const int cp = sc ^ ((row >> 1) & 3);                                       \
      gload_lds16(W + (size_t)(colBase + row) * 1024 + (kt) * 32 + cp * 8,        \
                  (dst) + (j * 4 + w) * 512 + l * 8);                             \
    }                                                                             \
  }

  // Compute tile kt from Bs[cb] + A regs R; cvt per-m keeps live regs low.
#define COMPUTE(cb, R)                                                            \
  {                                                                               \
    bf16x8 bfr[4];                                                                \
    _Pragma("unroll") for (int n = 0; n < 4; ++n)                                 \
        bfr[n] = *reinterpret_cast<const bf16x8*>(&Bs[cb][boff[n]]);              \
    _Pragma("unroll") for (int m = 0; m < 4; ++m) {                               \
      bf16x8 afm = cvt8(R[2 * m], R[2 * m + 1]);                                  \
      __builtin_amdgcn_s_setprio(1);                                              \
      _Pragma("unroll") for (int n = 0; n < 4; ++n)                               \
          acc[m][n] = __builtin_amdgcn_mfma_f32_16x16x32_bf16(afm, bfr[n],        \
                                                              acc[m][n], 0, 0, 0); \
      __builtin_amdgcn_s_setprio(0);                                              \
    }                                                                             \
  }

  f32x4 aRa[8], aRb[8];

  // ---- prologue.  VMEM order: A(0)x8, glds(0)x2, A(1)x8 -> vmcnt(8)
  // retires the 10 oldest = A(0)+glds(0); A(1) stays in flight.
  ISSUE_A(0, aRa);
  STAGE_B(&Bs[0][0], 0);
  ISSUE_A(1, aRb);
  WAIT_VM(8);
  SCHED0; BARRIER; SCHED0;

  // ---- main loop, manual 2-step unroll (static buffers + static reg pp).
  // Iter kt: stage B(kt+1); compute tile kt (A from regs, 2-iter-old);
  // issue A(kt+2); fence vmcnt(8): at that point outstanding =
  // A(kt+1)x8 + glds(kt+1)x2 + A(kt+2)x8 = 18 -> retires A(kt+1)+glds(kt+1).
  for (int kt = 0; kt < 32; kt += 2) {
    {  // even: cb=0, consume aRa=A(kt), refill aRa<-A(kt+2)
      STAGE_B(&Bs[1][0], kt + 1);
      SCHED0;                       // pin glds before this iter's A loads
      COMPUTE(0, aRa);
      if (kt + 2 < 32) ISSUE_A(kt + 2, aRa);
      WAIT_VM(8);
      SCHED0; BARRIER; SCHED0;
    }
    {  // odd: cb=1, consume aRb=A(kt+1), refill aRb<-A(kt+3)
      if (kt + 2 < 32) {
        STAGE_B(&Bs[0][0], kt + 2);
        SCHED0;
        COMPUTE(1, aRb);
        if (kt + 3 < 32) ISSUE_A(kt + 3, aRb);
        WAIT_VM(8);
        SCHED0; BARRIER; SCHED0;
      } else {
        COMPUTE(1, aRb);            // last tile: no stage, no fence
      }
    }
  }

  // ---- epilogue: C/D layout col=lane&15, row=(lane>>4)*4+reg
#pragma unroll
  for (int n = 0; n < 4; ++n) {
    const int col = colBase + wc * 64 + n * 16 + fr;
    const float bn = bias[col];
#pragma unroll
    for (int m = 0; m < 4; ++m) {
      const int row0 = rowBase + wr * 64 + m * 16 + fg * 4;
#pragma unroll
      for (int j = 0; j < 4; ++j)
        O[(size_t)(row0 + j) * 1024 + col] = f2bf(acc[m][n][j] + bn);
    }
  }
#undef ISSUE_A
#undef STAGE_B
#undef COMPUTE
}

// ------------------------------------------------------------------ attention
// thread = (n group, head h, d-quarter dq, row-half rh): 4 q-rows x 16 d-cols
// of the 8-key attention; QK partial dots reduced across 4 dq lanes.
__global__ __launch_bounds__(256) void attn_kernel(const unsigned short* __restrict__ QKV,
                                                   float* __restrict__ out) {
  const int t = threadIdx.x;
  const int lane = t & 63;
  const int dq = lane & 3;
  const int h = (lane >> 2) & 15;
  const int rh = (t >> 6) & 1;
  const int n = blockIdx.x * 2 + (t >> 7);

  const unsigned short* Q = QKV;
  const unsigned short* K = QKV + (size_t)8388608;
  const unsigned short* V = QKV + (size_t)16777216;
  const size_t gbase = (size_t)n * 8192;
  const int coff = h * 64 + dq * 16;

  float q[4][16];
#pragma unroll
  for (int r = 0; r < 4; ++r) {
    const unsigned short* qp = Q + gbase + (size_t)(rh * 4 + r) * 1024 + coff;
    u16x8 a = *reinterpret_cast<const u16x8*>(qp);
    u16x8 b = *reinterpret_cast<const u16x8*>(qp + 8);
#pragma unroll
    for (int c = 0; c < 8; ++c) { q[r][c] = bf2f(a[c]); q[r][8 + c] = bf2f(b[c]); }
  }

  float s[4][8];
#pragma unroll
  for (int r = 0; r < 4; ++r)
#pragma unroll
    for (int j = 0; j < 8; ++j) s[r][j] = 0.f;

#pragma unroll
  for (int j = 0; j < 8; ++j) {
    const unsigned short* kp = K + gbase + (size_t)j * 1024 + coff;
    u16x8 a = *reinterpret_cast<const u16x8*>(kp);
    u16x8 b = *reinterpret_cast<const u16x8*>(kp + 8);
    float kv[16];
#pragma unroll
    for (int c = 0; c < 8; ++c) { kv[c] = bf2f(a[c]); kv[8 + c] = bf2f(b[c]); }
#pragma unroll
    for (int r = 0; r < 4; ++r) {
      float acc = 0.f;
#pragma unroll
      for (int c = 0; c < 16; ++c) acc += q[r][c] * kv[c];
      s[r][j] += acc;
    }
  }

#pragma unroll
  for (int r = 0; r < 4; ++r)
#pragma unroll
    for (int j = 0; j < 8; ++j) {
      float v = s[r][j];
      v += __shfl_xor(v, 1, 64);
      v += __shfl_xor(v, 2, 64);
      s[r][j] = v;
    }

  float p[4][8];
#pragma unroll
  for (int r = 0; r < 4; ++r) {
    float mx = s[r][0];
#pragma unroll
    for (int j = 1; j < 8; ++j) mx = fmaxf(mx, s[r][j]);
    float sum = 0.f;
#pragma unroll
    for (int j = 0; j < 8; ++j) {
      float e = __expf(0.125f * (s[r][j] - mx));  // SCALE = 1/sqrt(64)
      p[r][j] = e;
      sum += e;
    }
    float inv = 1.f / sum;
#pragma unroll
    for (int j = 0; j < 8; ++j) p[r][j] *= inv;
  }

  float o[4][16];
#pragma unroll
  for (int r = 0; r < 4; ++r)
#pragma unroll
    for (int c = 0; c < 16; ++c) o[r][c] = 0.f;

#pragma unroll
  for (int j = 0; j < 8; ++j) {
    const unsigned short* vp = V + gbase + (size_t)j * 1024 + coff;
    u16x8 a = *reinterpret_cast<const u16x8*>(vp);
    u16x8 b = *reinterpret_cast<const u16x8*>(vp + 8);
    float vv[16];
#pragma unroll
    for (int c = 0; c < 8; ++c) { vv[c] = bf2f(a[c]); vv[8 + c] = bf2f(b[c]); }
#pragma unroll
    for (int r = 0; r < 4; ++r)
#pragma unroll
      for (int c = 0; c < 16; ++c) o[r][c] += p[r][j] * vv[c];
  }

#pragma unroll
  for (int r = 0; r < 4; ++r) {
    float* op = out + gbase + (size_t)(rh * 4 + r) * 1024 + coff;
    f32x4 v0 = {o[r][0], o[r][1], o[r][2], o[r][3]};
    f32x4 v1 = {o[r][4], o[r][5], o[r][6], o[r][7]};
    f32x4 v2 = {o[r][8], o[r][9], o[r][10], o[r][11]};
    f32x4 v3 = {o[r][12], o[r][13], o[r][14], o[r][15]};
    reinterpret_cast<f32x4*>(op)[0] = v0;
    reinterpret_cast<f32x4*>(op)[1] = v1;
    reinterpret_cast<f32x4*>(op)[2] = v2;
    reinterpret_cast<f32x4*>(op)[3] = v3;
  }
}

// ------------------------------------------------------------------- launch
extern "C" void kernel_launch(void* const* d_in, const int* in_sizes, int n_in,
                              void* d_out, int out_size, void* d_ws, size_t ws_size,
                              hipStream_t stream) {
  const float* Xq = (const float*)d_in[0];
  const float* Xk = (const float*)d_in[1];
  const float* Xv = (const float*)d_in[2];
  const float* Wq = (const float*)d_in[3];
  const float* bq = (const float*)d_in[4];
  const float* Wk = (const float*)d_in[5];
  const float* bk = (const float*)d_in[6];
  const float* Wv = (const float*)d_in[7];
  const float* bv = (const float*)d_in[8];

  unsigned short* ws = (unsigned short*)d_ws;
  unsigned short* Wb = ws;                              // 3 x 1M bf16 (6 MB), linear
  unsigned short* QKV = ws + (size_t)3 * 1024 * 1024;   // 3 x 8M bf16 (48 MB)

  cvt_w<<<1536, 256, 0, stream>>>(Wq, Wk, Wv, Wb);
  gemm12<<<1536, 256, 0, stream>>>(Xq, Xk, Xv, Wb, bq, bk, bv, QKV);
  attn_kernel<<<512, 256, 0, stream>>>(QKV, (float*)d_out);
}